// Round 3
// baseline (285.250 us; speedup 1.0000x reference)
//
#include <hip/hip_runtime.h>
#include <math.h>

#define NIMG 8
#define NCLS 19
#define IMG_H 512
#define IMG_W 512
#define HW (IMG_H * IMG_W)
#define NQ (HW / 4)              // 65536 quads per image
#define PPT 4                    // quads per thread (256-stride apart)
#define GRIDX (NQ / (256 * PPT)) // 64 blocks per image
#define NPIX (4 * PPT)           // 16 pixels per thread
#define BSTRIDE 21               // lane-bin row stride: gcd(21,32)=1 -> 2-way = free
#define TRASH 19                 // bin for invalid / gated-off pixels
#define GBINS(acc, n, c) (((acc) * NIMG + (n)) * NCLS + (c))

__device__ inline float wave_reduce_add(float v) {
    #pragma unroll
    for (int off = 32; off > 0; off >>= 1)
        v += __shfl_down(v, off, 64);
    return v;
}

// ---------------------------------------------------------------------------
// Burst-length variant. Previous rounds proved in-flight bytes / occupancy
// are NOT the limiter (93us at 176/208/352 KB-in-flight per CU alike, 2 TB/s
// effective read). Remaining hypothesis: HBM row/channel locality collapse
// from 22 interleaved 1MB-strided streams at 4KB-per-stream granularity.
// Here each block reads 16KB CONTIGUOUS per class (PPT=4 quads/thread,
// back-to-back), classes software-pipelined one ahead (prefetch c+1, consume
// c), and each block starts its class loop at a rotated offset (bx % 19) so
// the chip's instantaneous bursts spread across all 19 planes instead of
// marching in lockstep.
// ---------------------------------------------------------------------------
__global__ __launch_bounds__(256, 2) void main_kernel(
    const float* __restrict__ segin,
    const float* __restrict__ edgein,
    const int* __restrict__ segmask,
    const int* __restrict__ edgemask,
    float* __restrict__ g_bins,      // [4][NIMG][NCLS]
    float* __restrict__ g_sc)        // [NIMG][4]
{
    __shared__ float s_bins[4 * 64 * BSTRIDE];   // [acc][lane][class(21)]
    __shared__ float s_red[4][4];

    const int n = blockIdx.y;
    const int bx = blockIdx.x;
    const int tid = threadIdx.x;
    const int lane = tid & 63;
    const int wave = tid >> 6;

    for (int i = tid; i < 4 * 64 * BSTRIDE; i += 256) s_bins[i] = 0.f;
    __syncthreads();

    float* b_slpt = &s_bins[(0 * 64 + lane) * BSTRIDE];
    float* b_scnt = &s_bins[(1 * 64 + lane) * BSTRIDE];
    float* b_alpt = &s_bins[(2 * 64 + lane) * BSTRIDE];
    float* b_acnt = &s_bins[(3 * 64 + lane) * BSTRIDE];

    const float4* segq  = (const float4*)(segin  + (size_t)n * NCLS * HW);
    const float4* edgeq = (const float4*)(edgein + (size_t)n * HW);
    const int4*   smq   = (const int4*)(segmask  + (size_t)n * HW);
    const int4*   emq   = (const int4*)(edgemask + (size_t)n * HW);

    const int q0 = bx * (256 * PPT) + tid;   // block covers 1024 consecutive quads
    const int rot = bx % NCLS;               // per-block class rotation

    // ---- issue mask/edge bursts (3 x 16KB contiguous) + prefetch class 'rot'
    int4 t4[PPT], te4[PPT];
    float4 e4[PPT];
    #pragma unroll
    for (int k = 0; k < PPT; k++) t4[k]  = smq[q0 + 256 * k];
    #pragma unroll
    for (int k = 0; k < PPT; k++) te4[k] = emq[q0 + 256 * k];
    #pragma unroll
    for (int k = 0; k < PPT; k++) e4[k]  = edgeq[q0 + 256 * k];

    float4 xa[PPT], xb[PPT];
    #pragma unroll
    for (int k = 0; k < PPT; k++)
        xa[k] = segq[(size_t)rot * NQ + q0 + 256 * k];
    __builtin_amdgcn_sched_barrier(0);

    // ---- BCE + attention gates + target classes (masks arrive first) ----
    float bp = 0.f, bn = 0.f, pc = 0.f, nc = 0.f;
    unsigned gate = 0u;
    int tc[NPIX];
#define PREP1(E, TE, T, P) do { \
        const float b_ = fmaxf((E), 0.f) - (E) * (float)(TE) \
                         + __logf(1.f + __expf(-fabsf(E))); \
        if ((TE) == 1)      { bp += b_; pc += 1.f; } \
        else if ((TE) == 0) { bn += b_; nc += 1.f; } \
        gate |= ((E) > 0.8f ? 1u : 0u) << (P); \
        tc[P] = ((unsigned)(T) < NCLS) ? (T) : TRASH; \
    } while (0)
    #pragma unroll
    for (int k = 0; k < PPT; k++) {
        PREP1(e4[k].x, te4[k].x, t4[k].x, 4 * k + 0);
        PREP1(e4[k].y, te4[k].y, t4[k].y, 4 * k + 1);
        PREP1(e4[k].z, te4[k].z, t4[k].z, 4 * k + 2);
        PREP1(e4[k].w, te4[k].w, t4[k].w, 4 * k + 3);
    }
#undef PREP1

    // ---- rotated, software-pipelined class loop ----
    float se[NPIX], xt[NPIX];
    #pragma unroll
    for (int p = 0; p < NPIX; p++) { se[p] = 0.f; xt[p] = 0.f; }

    #pragma unroll
    for (int c = 0; c < NCLS; c++) {
        // issue next class's 16KB burst before consuming current
        if (c + 1 < NCLS) {
            int ca1 = c + 1 + rot; if (ca1 >= NCLS) ca1 -= NCLS;
            if (c & 1) {
                #pragma unroll
                for (int k = 0; k < PPT; k++)
                    xa[k] = segq[(size_t)ca1 * NQ + q0 + 256 * k];
            } else {
                #pragma unroll
                for (int k = 0; k < PPT; k++)
                    xb[k] = segq[(size_t)ca1 * NQ + q0 + 256 * k];
            }
        }
        __builtin_amdgcn_sched_barrier(0);

        int ca = c + rot; if (ca >= NCLS) ca -= NCLS;
        #pragma unroll
        for (int k = 0; k < PPT; k++) {
            const float4 v = (c & 1) ? xb[k] : xa[k];
            se[4*k+0] += __expf(v.x); xt[4*k+0] = (ca == tc[4*k+0]) ? v.x : xt[4*k+0];
            se[4*k+1] += __expf(v.y); xt[4*k+1] = (ca == tc[4*k+1]) ? v.y : xt[4*k+1];
            se[4*k+2] += __expf(v.z); xt[4*k+2] = (ca == tc[4*k+2]) ? v.z : xt[4*k+2];
            se[4*k+3] += __expf(v.w); xt[4*k+3] = (ca == tc[4*k+3]) ? v.w : xt[4*k+3];
        }
    }

    // ---- log-prob + branch-free LDS binning ----
    #pragma unroll
    for (int p = 0; p < NPIX; p++) {
        const float lp = xt[p] - __logf(se[p]);
        atomicAdd(&b_slpt[tc[p]], lp);
        atomicAdd(&b_scnt[tc[p]], 1.f);
        const int ta = ((gate >> p) & 1u) ? tc[p] : TRASH;
        atomicAdd(&b_alpt[ta], lp);
        atomicAdd(&b_acnt[ta], 1.f);
    }

    // ---- BCE block reduction ----
    bp = wave_reduce_add(bp);
    bn = wave_reduce_add(bn);
    pc = wave_reduce_add(pc);
    nc = wave_reduce_add(nc);
    if (lane == 0) { s_red[0][wave] = bp; s_red[1][wave] = bn;
                     s_red[2][wave] = pc; s_red[3][wave] = nc; }
    __syncthreads();

    if (tid < 4 * NCLS) {
        const int acc = tid / NCLS;
        const int c = tid - acc * NCLS;
        float s = 0.f;
        #pragma unroll 8
        for (int l = 0; l < 64; l++)
            s += s_bins[(acc * 64 + l) * BSTRIDE + c];
        atomicAdd(&g_bins[GBINS(acc, n, c)], s);
    } else if (tid < 4 * NCLS + 4) {
        const int k = tid - 4 * NCLS;
        atomicAdd(&g_sc[n * 4 + k],
                  s_red[k][0] + s_red[k][1] + s_red[k][2] + s_red[k][3]);
    }
}

// ---------------------------------------------------------------------------
// Finalize: weights from counts, weighted combines, 4 outputs. Reads 2.5 KB.
// ---------------------------------------------------------------------------
__global__ void final_kernel(const float* __restrict__ g_bins,
                             const float* __restrict__ g_sc,
                             float* __restrict__ out)
{
    __shared__ float s_seg[NIMG];
    __shared__ float s_att[NIMG];
    const int t = threadIdx.x;
    if (t < NIMG) {
        const int n = t;
        float tot = 0.f, tota = 0.f;
        for (int c = 0; c < NCLS; c++) {
            tot  += g_bins[GBINS(1, n, c)];
            tota += g_bins[GBINS(3, n, c)];
        }
        tot  = fmaxf(tot, 1.0f);
        tota = fmaxf(tota, 1.0f);
        float wp = 0.f, wplp = 0.f, wpa = 0.f, wplpa = 0.f;
        for (int c = 0; c < NCLS; c++) {
            const float cs = g_bins[GBINS(1, n, c)];
            const float ca = g_bins[GBINS(3, n, c)];
            const float w  = (cs > 0.f) ? (2.0f - cs / tot ) : 1.0f;
            const float wa = (ca > 0.f) ? (2.0f - ca / tota) : 1.0f;
            wp    += w * cs;    wplp  += w * g_bins[GBINS(0, n, c)];
            wpa   += wa * ca;   wplpa += wa * g_bins[GBINS(2, n, c)];
        }
        s_seg[n] = -wplp  / fmaxf(wp,  1e-12f);
        s_att[n] = -wplpa / fmaxf(wpa, 1e-12f);
    }
    __syncthreads();
    if (t == 0) {
        float seg = 0.f, att = 0.f, bpt = 0.f, bnt = 0.f, pct = 0.f, nct = 0.f;
        for (int n = 0; n < NIMG; n++) {
            seg += s_seg[n];
            att += s_att[n];
            bpt += g_sc[n * 4 + 0];
            bnt += g_sc[n * 4 + 1];
            pct += g_sc[n * 4 + 2];
            nct += g_sc[n * 4 + 3];
        }
        const float s = fmaxf(pct + nct, 1.0f);
        const float bce = (nct / s) * bpt + (pct / s) * bnt;
        out[0] = seg;
        out[1] = 20.0f * bce / (float)(NIMG * HW);
        out[2] = att;
        out[3] = 0.0f;
    }
}

extern "C" void kernel_launch(void* const* d_in, const int* in_sizes, int n_in,
                              void* d_out, int out_size, void* d_ws, size_t ws_size,
                              hipStream_t stream) {
    const float* segin    = (const float*)d_in[0];
    const float* edgein   = (const float*)d_in[1];
    const int*   segmask  = (const int*)d_in[2];
    const int*   edgemask = (const int*)d_in[3];
    float* out = (float*)d_out;

    float* g_bins = (float*)d_ws;                 // 4*8*19 = 608 floats
    float* g_sc   = g_bins + 4 * NIMG * NCLS;     // 8*4 = 32 floats

    hipMemsetAsync(d_ws, 0, (4 * NIMG * NCLS + 4 * NIMG) * sizeof(float), stream);

    main_kernel<<<dim3(GRIDX, NIMG), 256, 0, stream>>>(
        segin, edgein, segmask, edgemask, g_bins, g_sc);
    final_kernel<<<1, 64, 0, stream>>>(g_bins, g_sc, out);
}

// Round 4
// 284.496 us; speedup vs baseline: 1.0027x; 1.0027x over previous
//
#include <hip/hip_runtime.h>
#include <math.h>

#define NIMG 8
#define NCLS 19
#define IMG_H 512
#define IMG_W 512
#define HW (IMG_H * IMG_W)
#define NQ (HW / 4)              // 65536 quads per image
#define PPT 4                    // quads per thread per class
#define QPB (256 * PPT)          // 1024 quads per block (16 KB/class)
#define QPW (64 * PPT)           // 256 quads per wave (4 KB/class, CONTIGUOUS)
#define GRIDX (NQ / QPB)         // 64 blocks per image
#define NPIX (4 * PPT)           // 16 pixels per thread
#define BSTRIDE 21               // lane-bin row stride: gcd(21,32)=1 -> 2-way = free
#define TRASH 19                 // bin for invalid / gated-off pixels
#define GBINS(acc, n, c) (((acc) * NIMG + (n)) * NCLS + (c))

__device__ inline float wave_reduce_add(float v) {
    #pragma unroll
    for (int off = 32; off > 0; off >>= 1)
        v += __shfl_down(v, off, 64);
    return v;
}

// ---------------------------------------------------------------------------
// Wave-contiguous burst variant. Diagnosis so far: every prior round's waves
// had ALL outstanding loads aliased to one HBM-channel group / L2-set slice
// (class stride 1MB and q-stride 4KB both preserve the low address bits that
// pick channel+set), which explains why in-flight depth sweeps (176->352
// KB/CU) changed nothing: each wave was serialized on a narrow queue.
// Fix under test: wave-contiguous q mapping. Wave w covers quads
// [bx*1024 + w*256, +256) so each per-class burst is 4 KB CONTIGUOUS (its 4
// loads are consecutive 1KB quarters) -> spans the full channel interleave
// period and a full L2-set range. Classes are software-pipelined (prefetch
// c+1 while consuming c) and rotated per block. 512 blocks, 8 waves/CU,
// ~64 KB/CU in flight.
// ---------------------------------------------------------------------------
__global__ __launch_bounds__(256, 2) void main_kernel(
    const float* __restrict__ segin,
    const float* __restrict__ edgein,
    const int* __restrict__ segmask,
    const int* __restrict__ edgemask,
    float* __restrict__ g_bins,      // [4][NIMG][NCLS]
    float* __restrict__ g_sc)        // [NIMG][4]
{
    __shared__ float s_bins[4 * 64 * BSTRIDE];   // [acc][lane][class(21)]
    __shared__ float s_red[4][4];

    const int n = blockIdx.y;
    const int bx = blockIdx.x;
    const int tid = threadIdx.x;
    const int lane = tid & 63;
    const int wave = tid >> 6;

    for (int i = tid; i < 4 * 64 * BSTRIDE; i += 256) s_bins[i] = 0.f;
    __syncthreads();

    float* b_slpt = &s_bins[(0 * 64 + lane) * BSTRIDE];
    float* b_scnt = &s_bins[(1 * 64 + lane) * BSTRIDE];
    float* b_alpt = &s_bins[(2 * 64 + lane) * BSTRIDE];
    float* b_acnt = &s_bins[(3 * 64 + lane) * BSTRIDE];

    const float4* segq  = (const float4*)(segin  + (size_t)n * NCLS * HW);
    const float4* edgeq = (const float4*)(edgein + (size_t)n * HW);
    const int4*   smq   = (const int4*)(segmask  + (size_t)n * HW);
    const int4*   emq   = (const int4*)(edgemask + (size_t)n * HW);

    // wave-contiguous base: wave w owns quads [bx*QPB + w*QPW, +QPW)
    const int qw = bx * QPB + wave * QPW + lane;
    const int rot = bx % NCLS;               // per-block class rotation

    // ---- issue mask/edge bursts (wave-contiguous 4KB each) + class 'rot' ----
    int4 t4[PPT], te4[PPT];
    float4 e4[PPT];
    #pragma unroll
    for (int k = 0; k < PPT; k++) t4[k]  = smq[qw + 64 * k];
    #pragma unroll
    for (int k = 0; k < PPT; k++) te4[k] = emq[qw + 64 * k];
    #pragma unroll
    for (int k = 0; k < PPT; k++) e4[k]  = edgeq[qw + 64 * k];

    float4 xa[PPT], xb[PPT];
    #pragma unroll
    for (int k = 0; k < PPT; k++)
        xa[k] = segq[(size_t)rot * NQ + qw + 64 * k];
    __builtin_amdgcn_sched_barrier(0);

    // ---- BCE + attention gates + target classes (masks arrive first) ----
    float bp = 0.f, bn = 0.f, pc = 0.f, nc = 0.f;
    unsigned gate = 0u;
    int tc[NPIX];
#define PREP1(E, TE, T, P) do { \
        const float b_ = fmaxf((E), 0.f) - (E) * (float)(TE) \
                         + __logf(1.f + __expf(-fabsf(E))); \
        if ((TE) == 1)      { bp += b_; pc += 1.f; } \
        else if ((TE) == 0) { bn += b_; nc += 1.f; } \
        gate |= ((E) > 0.8f ? 1u : 0u) << (P); \
        tc[P] = ((unsigned)(T) < NCLS) ? (T) : TRASH; \
    } while (0)
    #pragma unroll
    for (int k = 0; k < PPT; k++) {
        PREP1(e4[k].x, te4[k].x, t4[k].x, 4 * k + 0);
        PREP1(e4[k].y, te4[k].y, t4[k].y, 4 * k + 1);
        PREP1(e4[k].z, te4[k].z, t4[k].z, 4 * k + 2);
        PREP1(e4[k].w, te4[k].w, t4[k].w, 4 * k + 3);
    }
#undef PREP1

    // ---- rotated, software-pipelined class loop ----
    float se[NPIX], xt[NPIX];
    #pragma unroll
    for (int p = 0; p < NPIX; p++) { se[p] = 0.f; xt[p] = 0.f; }

    #pragma unroll
    for (int c = 0; c < NCLS; c++) {
        // issue next class's wave-contiguous 4KB burst before consuming current
        if (c + 1 < NCLS) {
            int ca1 = c + 1 + rot; if (ca1 >= NCLS) ca1 -= NCLS;
            if (c & 1) {
                #pragma unroll
                for (int k = 0; k < PPT; k++)
                    xa[k] = segq[(size_t)ca1 * NQ + qw + 64 * k];
            } else {
                #pragma unroll
                for (int k = 0; k < PPT; k++)
                    xb[k] = segq[(size_t)ca1 * NQ + qw + 64 * k];
            }
        }
        __builtin_amdgcn_sched_barrier(0);

        int ca = c + rot; if (ca >= NCLS) ca -= NCLS;
        #pragma unroll
        for (int k = 0; k < PPT; k++) {
            const float4 v = (c & 1) ? xb[k] : xa[k];
            se[4*k+0] += __expf(v.x); xt[4*k+0] = (ca == tc[4*k+0]) ? v.x : xt[4*k+0];
            se[4*k+1] += __expf(v.y); xt[4*k+1] = (ca == tc[4*k+1]) ? v.y : xt[4*k+1];
            se[4*k+2] += __expf(v.z); xt[4*k+2] = (ca == tc[4*k+2]) ? v.z : xt[4*k+2];
            se[4*k+3] += __expf(v.w); xt[4*k+3] = (ca == tc[4*k+3]) ? v.w : xt[4*k+3];
        }
    }

    // ---- log-prob + branch-free LDS binning ----
    #pragma unroll
    for (int p = 0; p < NPIX; p++) {
        const float lp = xt[p] - __logf(se[p]);
        atomicAdd(&b_slpt[tc[p]], lp);
        atomicAdd(&b_scnt[tc[p]], 1.f);
        const int ta = ((gate >> p) & 1u) ? tc[p] : TRASH;
        atomicAdd(&b_alpt[ta], lp);
        atomicAdd(&b_acnt[ta], 1.f);
    }

    // ---- BCE block reduction ----
    bp = wave_reduce_add(bp);
    bn = wave_reduce_add(bn);
    pc = wave_reduce_add(pc);
    nc = wave_reduce_add(nc);
    if (lane == 0) { s_red[0][wave] = bp; s_red[1][wave] = bn;
                     s_red[2][wave] = pc; s_red[3][wave] = nc; }
    __syncthreads();

    if (tid < 4 * NCLS) {
        const int acc = tid / NCLS;
        const int c = tid - acc * NCLS;
        float s = 0.f;
        #pragma unroll 8
        for (int l = 0; l < 64; l++)
            s += s_bins[(acc * 64 + l) * BSTRIDE + c];
        atomicAdd(&g_bins[GBINS(acc, n, c)], s);
    } else if (tid < 4 * NCLS + 4) {
        const int k = tid - 4 * NCLS;
        atomicAdd(&g_sc[n * 4 + k],
                  s_red[k][0] + s_red[k][1] + s_red[k][2] + s_red[k][3]);
    }
}

// ---------------------------------------------------------------------------
// Finalize: weights from counts, weighted combines, 4 outputs. Reads 2.5 KB.
// ---------------------------------------------------------------------------
__global__ void final_kernel(const float* __restrict__ g_bins,
                             const float* __restrict__ g_sc,
                             float* __restrict__ out)
{
    __shared__ float s_seg[NIMG];
    __shared__ float s_att[NIMG];
    const int t = threadIdx.x;
    if (t < NIMG) {
        const int n = t;
        float tot = 0.f, tota = 0.f;
        for (int c = 0; c < NCLS; c++) {
            tot  += g_bins[GBINS(1, n, c)];
            tota += g_bins[GBINS(3, n, c)];
        }
        tot  = fmaxf(tot, 1.0f);
        tota = fmaxf(tota, 1.0f);
        float wp = 0.f, wplp = 0.f, wpa = 0.f, wplpa = 0.f;
        for (int c = 0; c < NCLS; c++) {
            const float cs = g_bins[GBINS(1, n, c)];
            const float ca = g_bins[GBINS(3, n, c)];
            const float w  = (cs > 0.f) ? (2.0f - cs / tot ) : 1.0f;
            const float wa = (ca > 0.f) ? (2.0f - ca / tota) : 1.0f;
            wp    += w * cs;    wplp  += w * g_bins[GBINS(0, n, c)];
            wpa   += wa * ca;   wplpa += wa * g_bins[GBINS(2, n, c)];
        }
        s_seg[n] = -wplp  / fmaxf(wp,  1e-12f);
        s_att[n] = -wplpa / fmaxf(wpa, 1e-12f);
    }
    __syncthreads();
    if (t == 0) {
        float seg = 0.f, att = 0.f, bpt = 0.f, bnt = 0.f, pct = 0.f, nct = 0.f;
        for (int n = 0; n < NIMG; n++) {
            seg += s_seg[n];
            att += s_att[n];
            bpt += g_sc[n * 4 + 0];
            bnt += g_sc[n * 4 + 1];
            pct += g_sc[n * 4 + 2];
            nct += g_sc[n * 4 + 3];
        }
        const float s = fmaxf(pct + nct, 1.0f);
        const float bce = (nct / s) * bpt + (pct / s) * bnt;
        out[0] = seg;
        out[1] = 20.0f * bce / (float)(NIMG * HW);
        out[2] = att;
        out[3] = 0.0f;
    }
}

extern "C" void kernel_launch(void* const* d_in, const int* in_sizes, int n_in,
                              void* d_out, int out_size, void* d_ws, size_t ws_size,
                              hipStream_t stream) {
    const float* segin    = (const float*)d_in[0];
    const float* edgein   = (const float*)d_in[1];
    const int*   segmask  = (const int*)d_in[2];
    const int*   edgemask = (const int*)d_in[3];
    float* out = (float*)d_out;

    float* g_bins = (float*)d_ws;                 // 4*8*19 = 608 floats
    float* g_sc   = g_bins + 4 * NIMG * NCLS;     // 8*4 = 32 floats

    hipMemsetAsync(d_ws, 0, (4 * NIMG * NCLS + 4 * NIMG) * sizeof(float), stream);

    main_kernel<<<dim3(GRIDX, NIMG), 256, 0, stream>>>(
        segin, edgein, segmask, edgemask, g_bins, g_sc);
    final_kernel<<<1, 64, 0, stream>>>(g_bins, g_sc, out);
}

// Round 6
// 268.713 us; speedup vs baseline: 1.0615x; 1.0587x over previous
//
#include <hip/hip_runtime.h>
#include <math.h>

#define NIMG 8
#define NCLS 19
#define IMG_H 512
#define IMG_W 512
#define HW (IMG_H * IMG_W)
#define NQ (HW / 4)          // 65536 quads per image
#define GRIDX 256            // one quad per thread: 256 blk x 256 thr = 65536 quads
#define BSTRIDE 21           // lane-bin row stride: gcd(21,32)=1 -> 2-way = free
#define TRASH 19             // bin for invalid / gated-off pixels
#define GBINS(acc, n, c) (((acc) * NIMG + (n)) * NCLS + (c))

// native clang vector type: __builtin_nontemporal_load requires a pointer to
// scalar/native-vector, not HIP_vector_type (a struct). Same 16B layout.
typedef float floatx4 __attribute__((ext_vector_type(4)));

__device__ inline float wave_reduce_add(float v) {
    #pragma unroll
    for (int off = 32; off > 0; off >>= 1)
        v += __shfl_down(v, off, 64);
    return v;
}

// ---------------------------------------------------------------------------
// Cache-policy probe on the proven-best structure (R2: one quad/thread,
// single 22-load batch, 16 waves/CU). Falsified so far: occupancy, in-flight
// depth (176->352KB/CU), burst length, channel de-aliasing, class rotation —
// all null at ~2.0 TB/s effective read. Hypothesis: service-rate cap on the
// L2-miss path for allocate-type reads. Last untested lever: NON-TEMPORAL
// loads on the 19 segin streams (86% of bytes) — nt bit may engage a
// streaming path / skip allocation. Masks+edge stay normal (small,
// latency-critical, consumed first).
// ---------------------------------------------------------------------------
__global__ __launch_bounds__(256, 4) void main_kernel(
    const float* __restrict__ segin,
    const float* __restrict__ edgein,
    const int* __restrict__ segmask,
    const int* __restrict__ edgemask,
    float* __restrict__ g_bins,      // [4][NIMG][NCLS]
    float* __restrict__ g_sc)        // [NIMG][4]
{
    __shared__ float s_bins[4 * 64 * BSTRIDE];   // [acc][lane][class(21)]
    __shared__ float s_red[4][4];

    const int n = blockIdx.y;
    const int bx = blockIdx.x;
    const int tid = threadIdx.x;
    const int lane = tid & 63;
    const int wave = tid >> 6;

    for (int i = tid; i < 4 * 64 * BSTRIDE; i += 256) s_bins[i] = 0.f;
    __syncthreads();

    float* b_slpt = &s_bins[(0 * 64 + lane) * BSTRIDE];
    float* b_scnt = &s_bins[(1 * 64 + lane) * BSTRIDE];
    float* b_alpt = &s_bins[(2 * 64 + lane) * BSTRIDE];
    float* b_acnt = &s_bins[(3 * 64 + lane) * BSTRIDE];

    const floatx4* segq = (const floatx4*)(segin  + (size_t)n * NCLS * HW);
    const float4* edgeq = (const float4*)(edgein + (size_t)n * HW);
    const int4*   smq   = (const int4*)(segmask  + (size_t)n * HW);
    const int4*   emq   = (const int4*)(edgemask + (size_t)n * HW);

    float bp = 0.f, bn = 0.f, pc = 0.f, nc = 0.f;

    const int q = bx * 256 + tid;

    // ---- issue every load (segin via nt), then pin the boundary ----
    const int4 t4  = smq[q];
    const int4 te4 = emq[q];
    const float4 e4 = edgeq[q];
    floatx4 xs[NCLS];
    #pragma unroll
    for (int c = 0; c < NCLS; c++)
        xs[c] = __builtin_nontemporal_load(&segq[(size_t)c * NQ + q]);
    __builtin_amdgcn_sched_barrier(0);

    // ---- BCE + attention gates (masks issued first: arrive first) ----
    unsigned gate = 0u;
#define BCE1(E, TE, GBIT) do { \
        const float b_ = fmaxf((E), 0.f) - (E) * (float)(TE) \
                         + __logf(1.f + __expf(-fabsf(E))); \
        if ((TE) == 1)      { bp += b_; pc += 1.f; } \
        else if ((TE) == 0) { bn += b_; nc += 1.f; } \
        gate |= ((E) > 0.8f ? 1u : 0u) << (GBIT); \
    } while (0)
    BCE1(e4.x, te4.x, 0); BCE1(e4.y, te4.y, 1);
    BCE1(e4.z, te4.z, 2); BCE1(e4.w, te4.w, 3);
#undef BCE1

    const int tc0 = ((unsigned)t4.x < NCLS) ? t4.x : TRASH;
    const int tc1 = ((unsigned)t4.y < NCLS) ? t4.y : TRASH;
    const int tc2 = ((unsigned)t4.z < NCLS) ? t4.z : TRASH;
    const int tc3 = ((unsigned)t4.w < NCLS) ? t4.w : TRASH;

    float se0 = 0.f, se1 = 0.f, se2 = 0.f, se3 = 0.f;
    float xt0 = 0.f, xt1 = 0.f, xt2 = 0.f, xt3 = 0.f;
    #pragma unroll
    for (int c = 0; c < NCLS; c++) {
        se0 += __expf(xs[c].x); xt0 = (c == tc0) ? xs[c].x : xt0;
        se1 += __expf(xs[c].y); xt1 = (c == tc1) ? xs[c].y : xt1;
        se2 += __expf(xs[c].z); xt2 = (c == tc2) ? xs[c].z : xt2;
        se3 += __expf(xs[c].w); xt3 = (c == tc3) ? xs[c].w : xt3;
    }
    const float lp0 = xt0 - __logf(se0);
    const float lp1 = xt1 - __logf(se1);
    const float lp2 = xt2 - __logf(se2);
    const float lp3 = xt3 - __logf(se3);

    // ---- branch-free LDS binning (trash bin absorbs invalid/ungated) ----
#define BIN1(TC, LP, GBIT) do { \
        atomicAdd(&b_slpt[(TC)], (LP)); \
        atomicAdd(&b_scnt[(TC)], 1.f); \
        const int ta_ = ((gate >> (GBIT)) & 1u) ? (TC) : TRASH; \
        atomicAdd(&b_alpt[ta_], (LP)); \
        atomicAdd(&b_acnt[ta_], 1.f); \
    } while (0)
    BIN1(tc0, lp0, 0); BIN1(tc1, lp1, 1);
    BIN1(tc2, lp2, 2); BIN1(tc3, lp3, 3);
#undef BIN1

    // ---- BCE block reduction ----
    bp = wave_reduce_add(bp);
    bn = wave_reduce_add(bn);
    pc = wave_reduce_add(pc);
    nc = wave_reduce_add(nc);
    if (lane == 0) { s_red[0][wave] = bp; s_red[1][wave] = bn;
                     s_red[2][wave] = pc; s_red[3][wave] = nc; }
    __syncthreads();

    if (tid < 4 * NCLS) {
        const int acc = tid / NCLS;
        const int c = tid - acc * NCLS;
        float s = 0.f;
        #pragma unroll 8
        for (int l = 0; l < 64; l++)
            s += s_bins[(acc * 64 + l) * BSTRIDE + c];
        atomicAdd(&g_bins[GBINS(acc, n, c)], s);
    } else if (tid < 4 * NCLS + 4) {
        const int k = tid - 4 * NCLS;
        atomicAdd(&g_sc[n * 4 + k],
                  s_red[k][0] + s_red[k][1] + s_red[k][2] + s_red[k][3]);
    }
}

// ---------------------------------------------------------------------------
// Finalize: weights from counts, weighted combines, 4 outputs. Reads 2.5 KB.
// ---------------------------------------------------------------------------
__global__ void final_kernel(const float* __restrict__ g_bins,
                             const float* __restrict__ g_sc,
                             float* __restrict__ out)
{
    __shared__ float s_seg[NIMG];
    __shared__ float s_att[NIMG];
    const int t = threadIdx.x;
    if (t < NIMG) {
        const int n = t;
        float tot = 0.f, tota = 0.f;
        for (int c = 0; c < NCLS; c++) {
            tot  += g_bins[GBINS(1, n, c)];
            tota += g_bins[GBINS(3, n, c)];
        }
        tot  = fmaxf(tot, 1.0f);
        tota = fmaxf(tota, 1.0f);
        float wp = 0.f, wplp = 0.f, wpa = 0.f, wplpa = 0.f;
        for (int c = 0; c < NCLS; c++) {
            const float cs = g_bins[GBINS(1, n, c)];
            const float ca = g_bins[GBINS(3, n, c)];
            const float w  = (cs > 0.f) ? (2.0f - cs / tot ) : 1.0f;
            const float wa = (ca > 0.f) ? (2.0f - ca / tota) : 1.0f;
            wp    += w * cs;    wplp  += w * g_bins[GBINS(0, n, c)];
            wpa   += wa * ca;   wplpa += wa * g_bins[GBINS(2, n, c)];
        }
        s_seg[n] = -wplp  / fmaxf(wp,  1e-12f);
        s_att[n] = -wplpa / fmaxf(wpa, 1e-12f);
    }
    __syncthreads();
    if (t == 0) {
        float seg = 0.f, att = 0.f, bpt = 0.f, bnt = 0.f, pct = 0.f, nct = 0.f;
        for (int n = 0; n < NIMG; n++) {
            seg += s_seg[n];
            att += s_att[n];
            bpt += g_sc[n * 4 + 0];
            bnt += g_sc[n * 4 + 1];
            pct += g_sc[n * 4 + 2];
            nct += g_sc[n * 4 + 3];
        }
        const float s = fmaxf(pct + nct, 1.0f);
        const float bce = (nct / s) * bpt + (pct / s) * bnt;
        out[0] = seg;
        out[1] = 20.0f * bce / (float)(NIMG * HW);
        out[2] = att;
        out[3] = 0.0f;
    }
}

extern "C" void kernel_launch(void* const* d_in, const int* in_sizes, int n_in,
                              void* d_out, int out_size, void* d_ws, size_t ws_size,
                              hipStream_t stream) {
    const float* segin    = (const float*)d_in[0];
    const float* edgein   = (const float*)d_in[1];
    const int*   segmask  = (const int*)d_in[2];
    const int*   edgemask = (const int*)d_in[3];
    float* out = (float*)d_out;

    float* g_bins = (float*)d_ws;                 // 4*8*19 = 608 floats
    float* g_sc   = g_bins + 4 * NIMG * NCLS;     // 8*4 = 32 floats

    hipMemsetAsync(d_ws, 0, (4 * NIMG * NCLS + 4 * NIMG) * sizeof(float), stream);

    main_kernel<<<dim3(GRIDX, NIMG), 256, 0, stream>>>(
        segin, edgein, segmask, edgemask, g_bins, g_sc);
    final_kernel<<<1, 64, 0, stream>>>(g_bins, g_sc, out);
}